// Round 1
// baseline (162.405 us; speedup 1.0000x reference)
//
#include <hip/hip_runtime.h>

#define HH 1024
#define WW 1024
#define NS 16

__global__ void init_bbox(int* __restrict__ bbox) {
    int i = threadIdx.x;
    if (i < NS) {
        bbox[i * 4 + 0] = HH;   // min row
        bbox[i * 4 + 1] = -1;   // max row
        bbox[i * 4 + 2] = WW;   // min col
        bbox[i * 4 + 3] = -1;   // max col
    }
}

__global__ void bbox_kernel(const float* __restrict__ mask, int* __restrict__ bbox) {
    const int s = blockIdx.y;
    const float4* m4 = (const float4*)(mask + (size_t)s * HH * WW);
    const int total4 = HH * WW / 4;
    int tid = blockIdx.x * blockDim.x + threadIdx.x;
    int stride = gridDim.x * blockDim.x;
    int minR = HH, maxR = -1, minC = WW, maxC = -1;
    for (int i = tid; i < total4; i += stride) {
        float4 v = m4[i];
        int base = i << 2;
        int row = base >> 10;        // WW = 1024
        int col = base & (WW - 1);
        bool a0 = v.x >= 0.5f, a1 = v.y >= 0.5f, a2 = v.z >= 0.5f, a3 = v.w >= 0.5f;
        if (a0 || a1 || a2 || a3) {
            minR = min(minR, row);
            maxR = max(maxR, row);
            int cmin = a0 ? col : (a1 ? col + 1 : (a2 ? col + 2 : col + 3));
            int cmax = a3 ? col + 3 : (a2 ? col + 2 : (a1 ? col + 1 : col));
            minC = min(minC, cmin);
            maxC = max(maxC, cmax);
        }
    }
    // 64-lane wave reduction
    for (int off = 32; off > 0; off >>= 1) {
        minR = min(minR, __shfl_down(minR, off));
        maxR = max(maxR, __shfl_down(maxR, off));
        minC = min(minC, __shfl_down(minC, off));
        maxC = max(maxC, __shfl_down(maxC, off));
    }
    __shared__ int sm[4][4];   // 256 threads = 4 waves
    int wave = threadIdx.x >> 6;
    int lane = threadIdx.x & 63;
    if (lane == 0) {
        sm[wave][0] = minR; sm[wave][1] = maxR; sm[wave][2] = minC; sm[wave][3] = maxC;
    }
    __syncthreads();
    if (threadIdx.x == 0) {
        int nw = blockDim.x >> 6;
        for (int wv = 1; wv < nw; ++wv) {
            minR = min(minR, sm[wv][0]);
            maxR = max(maxR, sm[wv][1]);
            minC = min(minC, sm[wv][2]);
            maxC = max(maxC, sm[wv][3]);
        }
        atomicMin(&bbox[s * 4 + 0], minR);
        atomicMax(&bbox[s * 4 + 1], maxR);
        atomicMin(&bbox[s * 4 + 2], minC);
        atomicMax(&bbox[s * 4 + 3], maxC);
    }
}

__global__ void resize_kernel(const float* __restrict__ mask,
                              const float* __restrict__ img,
                              const int* __restrict__ bbox,
                              float* __restrict__ out) {
    const int s  = blockIdx.z;
    const int oy = blockIdx.y;
    const int ox = blockIdx.x * blockDim.x + threadIdx.x;

    int minR = bbox[s * 4 + 0], maxR = bbox[s * 4 + 1];
    int minC = bbox[s * 4 + 2], maxC = bbox[s * 4 + 3];
    int xl, xr, yl, yr;
    if (maxR < 0) { xl = 0; xr = HH; } else { xl = max(minR - 1, 0); xr = maxR + 1; }
    if (maxC < 0) { yl = 0; yr = WW; } else { yl = max(minC - 1, 0); yr = maxC + 1; }
    int h = xr - xl, w = yr - yl;
    int c = min(h, w);
    int hstart = xl + (h - c) / 2;
    int wstart = yl + (w - c) / 2;

    float cf = (float)c;
    float sy = cf / (float)HH;   // out_h == HH
    float sx = cf / (float)WW;   // out_w == WW

    float ysf = fminf(fmaxf((oy + 0.5f) * sy - 0.5f, 0.0f), cf - 1.0f);
    int   y0i = (int)floorf(ysf);
    float wy  = ysf - (float)y0i;
    int   ry0 = hstart + y0i;
    int   ry1 = min(ry0 + 1, hstart + c - 1);

    float xsf = fminf(fmaxf((ox + 0.5f) * sx - 0.5f, 0.0f), cf - 1.0f);
    int   x0i = (int)floorf(xsf);
    float wx  = xsf - (float)x0i;
    int   rx0 = wstart + x0i;
    int   rx1 = min(rx0 + 1, wstart + c - 1);

    const float* msk = mask + (size_t)s * HH * WW;
    const float* im  = img  + (size_t)s * HH * WW * 3;

    float p00[3], p01[3], p10[3], p11[3];
    auto fetch = [&](int y, int x, float* p) {
        int idx = y * WW + x;
        float mv = msk[idx];
        if (mv >= 0.5f) {
            const float* q = im + (size_t)idx * 3;
            p[0] = q[0]; p[1] = q[1]; p[2] = q[2];
        } else {
            p[0] = 0.0f; p[1] = 0.0f; p[2] = 0.0f;
        }
    };
    fetch(ry0, rx0, p00);
    fetch(ry0, rx1, p01);
    fetch(ry1, rx0, p10);
    fetch(ry1, rx1, p11);

    float* o = out + ((size_t)s * HH * WW + (size_t)oy * WW + ox) * 3;
#pragma unroll
    for (int ch = 0; ch < 3; ++ch) {
        float top = (1.0f - wx) * p00[ch] + wx * p01[ch];
        float bot = (1.0f - wx) * p10[ch] + wx * p11[ch];
        o[ch] = (1.0f - wy) * top + wy * bot;
    }
}

extern "C" void kernel_launch(void* const* d_in, const int* in_sizes, int n_in,
                              void* d_out, int out_size, void* d_ws, size_t ws_size,
                              hipStream_t stream) {
    const float* masks  = (const float*)d_in[0];
    const float* images = (const float*)d_in[1];
    float* out = (float*)d_out;
    int* bbox = (int*)d_ws;

    init_bbox<<<1, 64, 0, stream>>>(bbox);
    bbox_kernel<<<dim3(32, NS), 256, 0, stream>>>(masks, bbox);
    resize_kernel<<<dim3(WW / 256, HH, NS), 256, 0, stream>>>(masks, images, bbox, out);
}

// Round 2
// 111.503 us; speedup vs baseline: 1.4565x; 1.4565x over previous
//
#include <hip/hip_runtime.h>

#define HH 1024
#define WW 1024
#define NS 16

__global__ void init_bbox(int* __restrict__ bbox) {
    int i = threadIdx.x;
    if (i < NS) {
        bbox[i * 4 + 0] = HH;   // min row
        bbox[i * 4 + 1] = -1;   // max row
        bbox[i * 4 + 2] = WW;   // min col
        bbox[i * 4 + 3] = -1;   // max col
    }
}

__global__ void bbox_kernel(const float* __restrict__ mask, int* __restrict__ bbox) {
    const int s = blockIdx.y;
    const float4* m4 = (const float4*)(mask + (size_t)s * HH * WW);
    const int total4 = HH * WW / 4;
    int tid = blockIdx.x * blockDim.x + threadIdx.x;
    int stride = gridDim.x * blockDim.x;
    int minR = HH, maxR = -1, minC = WW, maxC = -1;
    for (int i = tid; i < total4; i += stride) {
        float4 v = m4[i];
        int base = i << 2;
        int row = base >> 10;        // WW = 1024
        int col = base & (WW - 1);
        bool a0 = v.x >= 0.5f, a1 = v.y >= 0.5f, a2 = v.z >= 0.5f, a3 = v.w >= 0.5f;
        if (a0 || a1 || a2 || a3) {
            minR = min(minR, row);
            maxR = max(maxR, row);
            int cmin = a0 ? col : (a1 ? col + 1 : (a2 ? col + 2 : col + 3));
            int cmax = a3 ? col + 3 : (a2 ? col + 2 : (a1 ? col + 1 : col));
            minC = min(minC, cmin);
            maxC = max(maxC, cmax);
        }
    }
    // 64-lane wave reduction
    for (int off = 32; off > 0; off >>= 1) {
        minR = min(minR, __shfl_down(minR, off));
        maxR = max(maxR, __shfl_down(maxR, off));
        minC = min(minC, __shfl_down(minC, off));
        maxC = max(maxC, __shfl_down(maxC, off));
    }
    __shared__ int sm[4][4];   // 256 threads = 4 waves
    int wave = threadIdx.x >> 6;
    int lane = threadIdx.x & 63;
    if (lane == 0) {
        sm[wave][0] = minR; sm[wave][1] = maxR; sm[wave][2] = minC; sm[wave][3] = maxC;
    }
    __syncthreads();
    if (threadIdx.x == 0) {
        int nw = blockDim.x >> 6;
        for (int wv = 1; wv < nw; ++wv) {
            minR = min(minR, sm[wv][0]);
            maxR = max(maxR, sm[wv][1]);
            minC = min(minC, sm[wv][2]);
            maxC = max(maxC, sm[wv][3]);
        }
        atomicMin(&bbox[s * 4 + 0], minR);
        atomicMax(&bbox[s * 4 + 1], maxR);
        atomicMin(&bbox[s * 4 + 2], minC);
        atomicMax(&bbox[s * 4 + 3], maxC);
    }
}

// One block per output row (256 threads x 4 pixels). Identity-crop fast path
// does pure float4 masked copy; general path falls back to scalar bilinear.
__global__ void resize_kernel(const float* __restrict__ mask,
                              const float* __restrict__ img,
                              const int* __restrict__ bbox,
                              float* __restrict__ out) {
    const int s  = blockIdx.z;
    const int oy = blockIdx.y;
    const int ox4 = threadIdx.x * 4;   // first of 4 pixels this thread owns

    int minR = bbox[s * 4 + 0], maxR = bbox[s * 4 + 1];
    int minC = bbox[s * 4 + 2], maxC = bbox[s * 4 + 3];
    int xl, xr, yl, yr;
    if (maxR < 0) { xl = 0; xr = HH; } else { xl = max(minR - 1, 0); xr = maxR + 1; }
    if (maxC < 0) { yl = 0; yr = WW; } else { yl = max(minC - 1, 0); yr = maxC + 1; }
    int h = xr - xl, w = yr - yl;
    int c = min(h, w);
    int hstart = xl + (h - c) / 2;
    int wstart = yl + (w - c) / 2;

    const float* msk = mask + (size_t)s * HH * WW;
    const float* im  = img  + (size_t)s * HH * WW * 3;
    float* orow = out + ((size_t)s * HH * WW + (size_t)oy * WW) * 3;

    if (c == HH && c == WW && hstart == 0 && wstart == 0) {
        // Identity resample: out = (mask >= 0.5) ? img : 0, elementwise.
        int idx = oy * WW + ox4;                      // pixel index, multiple of 4
        float4 m = *(const float4*)(msk + idx);
        const float4* ip = (const float4*)(im + (size_t)idx * 3);
        float4 i0 = ip[0], i1 = ip[1], i2 = ip[2];
        float4 o0, o1, o2;
        bool m0 = m.x >= 0.5f, m1 = m.y >= 0.5f, m2 = m.z >= 0.5f, m3 = m.w >= 0.5f;
        o0.x = m0 ? i0.x : 0.0f;  o0.y = m0 ? i0.y : 0.0f;  o0.z = m0 ? i0.z : 0.0f;
        o0.w = m1 ? i0.w : 0.0f;
        o1.x = m1 ? i1.x : 0.0f;  o1.y = m1 ? i1.y : 0.0f;
        o1.z = m2 ? i1.z : 0.0f;  o1.w = m2 ? i1.w : 0.0f;
        o2.x = m2 ? i2.x : 0.0f;
        o2.y = m3 ? i2.y : 0.0f;  o2.z = m3 ? i2.z : 0.0f;  o2.w = m3 ? i2.w : 0.0f;
        float4* op = (float4*)(orow + (size_t)ox4 * 3);
        op[0] = o0; op[1] = o1; op[2] = o2;
        return;
    }

    // General path: scalar bilinear gather per pixel.
    float cf = (float)c;
    float sy = cf / (float)HH;
    float sx = cf / (float)WW;

    float ysf = fminf(fmaxf((oy + 0.5f) * sy - 0.5f, 0.0f), cf - 1.0f);
    int   y0i = (int)floorf(ysf);
    float wy  = ysf - (float)y0i;
    int   ry0 = hstart + y0i;
    int   ry1 = min(ry0 + 1, hstart + c - 1);

    for (int k = 0; k < 4; ++k) {
        int ox = ox4 + k;
        float xsf = fminf(fmaxf((ox + 0.5f) * sx - 0.5f, 0.0f), cf - 1.0f);
        int   x0i = (int)floorf(xsf);
        float wx  = xsf - (float)x0i;
        int   rx0 = wstart + x0i;
        int   rx1 = min(rx0 + 1, wstart + c - 1);

        float p00[3], p01[3], p10[3], p11[3];
        auto fetch = [&](int y, int x, float* p) {
            int idx = y * WW + x;
            float mv = msk[idx];
            if (mv >= 0.5f) {
                const float* q = im + (size_t)idx * 3;
                p[0] = q[0]; p[1] = q[1]; p[2] = q[2];
            } else {
                p[0] = 0.0f; p[1] = 0.0f; p[2] = 0.0f;
            }
        };
        fetch(ry0, rx0, p00);
        fetch(ry0, rx1, p01);
        fetch(ry1, rx0, p10);
        fetch(ry1, rx1, p11);

        float* o = orow + (size_t)ox * 3;
#pragma unroll
        for (int ch = 0; ch < 3; ++ch) {
            float top = (1.0f - wx) * p00[ch] + wx * p01[ch];
            float bot = (1.0f - wx) * p10[ch] + wx * p11[ch];
            o[ch] = (1.0f - wy) * top + wy * bot;
        }
    }
}

extern "C" void kernel_launch(void* const* d_in, const int* in_sizes, int n_in,
                              void* d_out, int out_size, void* d_ws, size_t ws_size,
                              hipStream_t stream) {
    const float* masks  = (const float*)d_in[0];
    const float* images = (const float*)d_in[1];
    float* out = (float*)d_out;
    int* bbox = (int*)d_ws;

    init_bbox<<<1, 64, 0, stream>>>(bbox);
    bbox_kernel<<<dim3(32, NS), 256, 0, stream>>>(masks, bbox);
    resize_kernel<<<dim3(1, HH, NS), 256, 0, stream>>>(masks, images, bbox, out);
}

// Round 3
// 94.034 us; speedup vs baseline: 1.7271x; 1.1858x over previous
//
#include <hip/hip_runtime.h>

#define HH 1024
#define WW 1024
#define NS 16

// ---------------------------------------------------------------------------
// Pass 1: one block per (row, sample). Threshold+bit-pack the mask row
// (1024 bits = 32 u32), and compute per-row min/max occupied column.
// ---------------------------------------------------------------------------
__global__ __launch_bounds__(256)
void pack_kernel(const float* __restrict__ mask,
                 unsigned int* __restrict__ packed,
                 int* __restrict__ rowMinC,
                 int* __restrict__ rowMaxC) {
    const int row = blockIdx.x;
    const int s   = blockIdx.y;
    const int t   = threadIdx.x;

    const float4* m4 = (const float4*)(mask + ((size_t)s * HH + row) * WW);
    float4 v = m4[t];                       // unit-stride, fully coalesced
    unsigned int n = (v.x >= 0.5f ? 1u : 0u)
                   | (v.y >= 0.5f ? 2u : 0u)
                   | (v.z >= 0.5f ? 4u : 0u)
                   | (v.w >= 0.5f ? 8u : 0u);

    __shared__ unsigned char nib[256];
    nib[t] = (unsigned char)n;

    // per-thread min/max col (col = 4t .. 4t+3)
    int col = t << 2;
    int cmin = WW, cmax = -1;
    if (n) {
        cmin = (n & 1) ? col : ((n & 2) ? col + 1 : ((n & 4) ? col + 2 : col + 3));
        cmax = (n & 8) ? col + 3 : ((n & 4) ? col + 2 : ((n & 2) ? col + 1 : col));
    }
    for (int off = 32; off > 0; off >>= 1) {
        cmin = min(cmin, __shfl_down(cmin, off));
        cmax = max(cmax, __shfl_down(cmax, off));
    }
    __shared__ int sm[4][2];
    int wave = t >> 6, lane = t & 63;
    if (lane == 0) { sm[wave][0] = cmin; sm[wave][1] = cmax; }
    __syncthreads();

    if (t < 32) {
        // assemble packed word from 8 nibbles
        unsigned int w = 0;
        const unsigned char* p = &nib[t << 3];
#pragma unroll
        for (int j = 0; j < 8; ++j) w |= ((unsigned int)p[j]) << (j << 2);
        packed[((size_t)s * HH + row) * 32 + t] = w;
    }
    if (t == 0) {
        for (int wv = 1; wv < 4; ++wv) {
            cmin = min(cmin, sm[wv][0]);
            cmax = max(cmax, sm[wv][1]);
        }
        rowMinC[s * HH + row] = cmin;
        rowMaxC[s * HH + row] = cmax;
    }
}

// ---------------------------------------------------------------------------
// Pass 2: one block per sample reduces 1024 row stats -> bbox (no atomics).
// ---------------------------------------------------------------------------
__global__ __launch_bounds__(256)
void reduce_kernel(const int* __restrict__ rowMinC,
                   const int* __restrict__ rowMaxC,
                   int* __restrict__ bbox) {
    const int s = blockIdx.x;
    const int t = threadIdx.x;
    int minR = HH, maxR = -1, minC = WW, maxC = -1;
    for (int m = 0; m < HH / 256; ++m) {
        int r = t + (m << 8);
        int mc = rowMaxC[s * HH + r];
        if (mc >= 0) {
            minR = min(minR, r);
            maxR = max(maxR, r);
            minC = min(minC, rowMinC[s * HH + r]);
            maxC = max(maxC, mc);
        }
    }
    for (int off = 32; off > 0; off >>= 1) {
        minR = min(minR, __shfl_down(minR, off));
        maxR = max(maxR, __shfl_down(maxR, off));
        minC = min(minC, __shfl_down(minC, off));
        maxC = max(maxC, __shfl_down(maxC, off));
    }
    __shared__ int sm[4][4];
    int wave = t >> 6, lane = t & 63;
    if (lane == 0) { sm[wave][0] = minR; sm[wave][1] = maxR; sm[wave][2] = minC; sm[wave][3] = maxC; }
    __syncthreads();
    if (t == 0) {
        for (int wv = 1; wv < 4; ++wv) {
            minR = min(minR, sm[wv][0]);
            maxR = max(maxR, sm[wv][1]);
            minC = min(minC, sm[wv][2]);
            maxC = max(maxC, sm[wv][3]);
        }
        bbox[s * 4 + 0] = minR;
        bbox[s * 4 + 1] = maxR;
        bbox[s * 4 + 2] = minC;
        bbox[s * 4 + 3] = maxC;
    }
}

// ---------------------------------------------------------------------------
// Pass 3: one block per (row, sample). Identity fast path: flat float4
// masked copy with packed-bit mask from LDS. General path: scalar bilinear.
// ---------------------------------------------------------------------------
__global__ __launch_bounds__(256)
void resize_kernel(const float* __restrict__ mask,
                   const float* __restrict__ img,
                   const unsigned int* __restrict__ packed,
                   const int* __restrict__ bbox,
                   float* __restrict__ out) {
    const int row = blockIdx.x;
    const int s   = blockIdx.y;
    const int t   = threadIdx.x;

    __shared__ unsigned int pw[32];
    if (t < 32) pw[t] = packed[((size_t)s * HH + row) * 32 + t];

    int minR = bbox[s * 4 + 0], maxR = bbox[s * 4 + 1];
    int minC = bbox[s * 4 + 2], maxC = bbox[s * 4 + 3];
    int xl, xr, yl, yr;
    if (maxR < 0) { xl = 0; xr = HH; } else { xl = max(minR - 1, 0); xr = maxR + 1; }
    if (maxC < 0) { yl = 0; yr = WW; } else { yl = max(minC - 1, 0); yr = maxC + 1; }
    int h = xr - xl, w = yr - yl;
    int c = min(h, w);
    int hstart = xl + (h - c) / 2;
    int wstart = yl + (w - c) / 2;

    const float* im   = img + (size_t)s * HH * WW * 3;
    float*       orow = out + ((size_t)s * HH + row) * WW * 3;

    __syncthreads();

    if (c == HH && c == WW && hstart == 0 && wstart == 0) {
        // Identity resample: out = bit(pixel) ? img : 0, flat float4 layout.
        const float4* ip = (const float4*)(im + (size_t)row * WW * 3);
        float4*       op = (float4*)orow;
#pragma unroll
        for (int j = 0; j < 3; ++j) {
            int fi = t + (j << 8);          // float4 index in row, 0..767
            int F  = fi << 2;               // float offset, 0..3068
            int p0 = F / 3;                 // first pixel covered
            int r  = F - p0 * 3;            // 0..2
            unsigned int b0 = (pw[p0 >> 5] >> (p0 & 31)) & 1u;
            int p1 = p0 + 1;
            unsigned int b1 = (pw[p1 >> 5] >> (p1 & 31)) & 1u;
            float4 v = ip[fi];
            float4 o;
            o.x = b0 ? v.x : 0.0f;                       // k=0 always pixel p0
            o.y = ((r < 2) ? b0 : b1) ? v.y : 0.0f;
            o.z = ((r == 0) ? b0 : b1) ? v.z : 0.0f;
            o.w = b1 ? v.w : 0.0f;                       // k=3 always pixel p1
            op[fi] = o;
        }
        return;
    }

    // General path: scalar bilinear gather per pixel (4 pixels/thread).
    const float* msk = mask + (size_t)s * HH * WW;
    float cf = (float)c;
    float sy = cf / (float)HH;
    float sx = cf / (float)WW;

    float ysf = fminf(fmaxf((row + 0.5f) * sy - 0.5f, 0.0f), cf - 1.0f);
    int   y0i = (int)floorf(ysf);
    float wy  = ysf - (float)y0i;
    int   ry0 = hstart + y0i;
    int   ry1 = min(ry0 + 1, hstart + c - 1);

    for (int k = 0; k < 4; ++k) {
        int ox = (t << 2) + k;
        float xsf = fminf(fmaxf((ox + 0.5f) * sx - 0.5f, 0.0f), cf - 1.0f);
        int   x0i = (int)floorf(xsf);
        float wx  = xsf - (float)x0i;
        int   rx0 = wstart + x0i;
        int   rx1 = min(rx0 + 1, wstart + c - 1);

        float p00[3], p01[3], p10[3], p11[3];
        auto fetch = [&](int y, int x, float* p) {
            int idx = y * WW + x;
            float mv = msk[idx];
            if (mv >= 0.5f) {
                const float* q = im + (size_t)idx * 3;
                p[0] = q[0]; p[1] = q[1]; p[2] = q[2];
            } else {
                p[0] = 0.0f; p[1] = 0.0f; p[2] = 0.0f;
            }
        };
        fetch(ry0, rx0, p00);
        fetch(ry0, rx1, p01);
        fetch(ry1, rx0, p10);
        fetch(ry1, rx1, p11);

        float* o = orow + (size_t)ox * 3;
#pragma unroll
        for (int ch = 0; ch < 3; ++ch) {
            float top = (1.0f - wx) * p00[ch] + wx * p01[ch];
            float bot = (1.0f - wx) * p10[ch] + wx * p11[ch];
            o[ch] = (1.0f - wy) * top + wy * bot;
        }
    }
}

extern "C" void kernel_launch(void* const* d_in, const int* in_sizes, int n_in,
                              void* d_out, int out_size, void* d_ws, size_t ws_size,
                              hipStream_t stream) {
    const float* masks  = (const float*)d_in[0];
    const float* images = (const float*)d_in[1];
    float* out = (float*)d_out;

    // workspace layout
    int* ws            = (int*)d_ws;
    int* bbox          = ws;                       // 16*4 ints
    int* rowMinC       = ws + 64;                  // NS*HH ints
    int* rowMaxC       = rowMinC + NS * HH;        // NS*HH ints
    unsigned int* pk   = (unsigned int*)(rowMaxC + NS * HH);  // NS*HH*32 u32

    pack_kernel  <<<dim3(HH, NS), 256, 0, stream>>>(masks, pk, rowMinC, rowMaxC);
    reduce_kernel<<<NS,           256, 0, stream>>>(rowMinC, rowMaxC, bbox);
    resize_kernel<<<dim3(HH, NS), 256, 0, stream>>>(masks, images, pk, bbox, out);
}